// Round 6
// baseline (459.176 us; speedup 1.0000x reference)
//
#include <hip/hip_runtime.h>

#define TEX_H 256
#define TEX_W 256
#define FCH 16
#define NPIX (8 * 256 * 256)
#define TS 16                 // texel tile = 16x16
#define NTILES 256            // 16x16 tiles
#define CAP 4096              // entries per tile bucket (mean ~1300, +77 sigma)

#define SQRT2_F 1.41421356237f
// Interior weights: du,dv relative to u are {0,1,2} exactly (grid anchored at u-2),
// so w is one of {1, exp(-sqrt(2)), exp(-2)}; slots at distance 2 fail w>0.1.
#define W_EDGE   0.24311673443f   // exp(-sqrt(2))
#define W_DIAG   0.13533528324f   // exp(-2)

// Entry packing: bit31 = boundary flag; bits30-26 = dr (center row - tile_r0 + 1,
// 0..17); bits25-21 = dc; bits18-0 = pixel id (NPIX = 2^19).
__global__ __launch_bounds__(256) void bin_kernel(
    const float2* __restrict__ uv_map,
    const float*  __restrict__ mask,
    int*          __restrict__ counts,
    unsigned int* __restrict__ entries)
{
    int pix = blockIdx.x * 256 + threadIdx.x;
    if (pix >= NPIX) return;
    if (mask[pix] == 0.0f) return;

    float2 uv = uv_map[pix];
    float u = uv.x * (float)TEX_W;
    float v = uv.y * (float)TEX_H;
    bool interior = (u >= 2.0f) && (v >= 2.0f);

    int iu = (int)u, iv = (int)v;
    int clo, chi, rlo, rhi;
    if (u >= 2.0f) { clo = iu - 1; chi = min(iu + 1, TEX_W - 1); }
    else           { clo = 0;      chi = 3; }            // slots 0..3, all in tile col 0
    if (v >= 2.0f) { rlo = iv - 1; rhi = min(iv + 1, TEX_H - 1); }
    else           { rlo = 0;      rhi = 3; }

    int trlo = rlo >> 4, trhi = rhi >> 4;
    int tclo = clo >> 4, tchi = chi >> 4;
    for (int tr = trlo; tr <= trhi; ++tr) {
        for (int tc = tclo; tc <= tchi; ++tc) {
            int t = tr * 16 + tc;
            int slot = atomicAdd(&counts[t], 1);
            if (slot < CAP) {
                unsigned int ent;
                if (interior) {
                    unsigned dr = (unsigned)(iv - (tr << 4) + 1);   // 0..17
                    unsigned dc = (unsigned)(iu - (tc << 4) + 1);
                    ent = (dr << 26) | (dc << 21) | (unsigned)pix;
                } else {
                    ent = (1u << 31) | (unsigned)pix;
                }
                entries[t * CAP + slot] = ent;
            }
        }
    }
}

// One workgroup per 16x16 texel tile. Accumulate in LDS, normalize, write the
// 8 broadcast batch copies directly. No global csum/wsum, no global atomics.
__global__ __launch_bounds__(512) void gather_kernel(
    const float*  __restrict__ f_map,
    const float2* __restrict__ uv_map,
    const int*    __restrict__ counts,
    const unsigned int* __restrict__ entries,
    float* __restrict__ out)
{
    __shared__ float s_csum[TS * TS * FCH];   // 16 KB
    __shared__ float s_wsum[TS * TS];         // 1 KB

    for (int i = threadIdx.x; i < TS * TS * FCH; i += 512) s_csum[i] = 0.0f;
    for (int i = threadIdx.x; i < TS * TS;       i += 512) s_wsum[i] = 0.0f;
    __syncthreads();

    int tile = blockIdx.x;
    int r0 = (tile >> 4) << 4;
    int c0 = (tile & 15) << 4;
    int cnt = counts[tile];
    if (cnt > CAP) cnt = CAP;

    int g = threadIdx.x >> 4;     // 32 entry-groups of 16 channel-lanes
    int c = threadIdx.x & 15;

    for (int e = g; e < cnt; e += 32) {
        unsigned ent = entries[tile * CAP + e];
        unsigned pix = ent & 0x7FFFFu;
        float f = f_map[pix * FCH + c];       // 16 lanes -> one 64B line

        if (!(ent >> 31)) {
            // Interior: 3x3 footprint, constant weights.
            int iv = r0 + (int)((ent >> 26) & 31u) - 1;
            int iu = c0 + (int)((ent >> 21) & 31u) - 1;
            #pragma unroll
            for (int dv = -1; dv <= 1; ++dv) {
                int lr = iv + dv - r0;
                if (lr < 0 || lr >= TS) continue;     // in-tile <=> valid & owned here
                #pragma unroll
                for (int du = -1; du <= 1; ++du) {
                    int lc = iu + du - c0;
                    if (lc < 0 || lc >= TS) continue;
                    float w = (dv == 0 && du == 0) ? 1.0f
                            : ((dv == 0 || du == 0) ? W_EDGE : W_DIAG);
                    atomicAdd(&s_csum[(lr * TS + lc) * FCH + c], w * f);
                    if (c == 0) atomicAdd(&s_wsum[lr * TS + lc], w);
                }
            }
        } else {
            // Boundary pixel (u<2 or v<2, ~1.6%): exact reference 4x4 window.
            float2 uvv = uv_map[pix];
            float u = uvv.x * (float)TEX_W;
            float v = uvv.y * (float)TEX_H;
            float us = fmaxf(u - 2.0f, 0.0f);
            float vs = fmaxf(v - 2.0f, 0.0f);
            #pragma unroll
            for (int kv = 0; kv < 4; ++kv) {
                float vg = vs + (float)kv;
                int lr = (int)vg - r0;
                if (lr < 0 || lr >= TS) continue;
                float dvf = fabsf(vg - v);
                #pragma unroll
                for (int ku = 0; ku < 4; ++ku) {
                    float ug = us + (float)ku;
                    int lc = (int)ug - c0;
                    if (lc < 0 || lc >= TS) continue;
                    float duf = fabsf(ug - u);
                    float w = expf(-sqrtf(duf * duf + dvf * dvf) * SQRT2_F);
                    if (w > 0.1f) {
                        atomicAdd(&s_csum[(lr * TS + lc) * FCH + c], w * f);
                        if (c == 0) atomicAdd(&s_wsum[lr * TS + lc], w);
                    }
                }
            }
        }
    }
    __syncthreads();

    // Normalize + broadcast to 8 batch copies. 1024 float4 slots.
    for (int i4 = threadIdx.x; i4 < TS * TS * FCH / 4; i4 += 512) {
        int texel = i4 >> 2;
        int q     = i4 & 3;
        int row = texel >> 4, col = texel & 15;
        float wv = s_wsum[texel];
        float s = (wv > 0.01f) ? (1.0f / (wv + 0.001f)) : 0.0f;
        float4 val = *(const float4*)&s_csum[texel * FCH + q * 4];
        val.x *= s; val.y *= s; val.z *= s; val.w *= s;
        size_t base = (((size_t)(r0 + row)) * TEX_W + (c0 + col)) * FCH + q * 4;
        #pragma unroll
        for (int b = 0; b < 8; ++b) {
            *(float4*)&out[(size_t)b * TEX_H * TEX_W * FCH + base] = val;
        }
    }
}

extern "C" void kernel_launch(void* const* d_in, const int* in_sizes, int n_in,
                              void* d_out, int out_size, void* d_ws, size_t ws_size,
                              hipStream_t stream) {
    const float*  f_map  = (const float*)d_in[0];
    const float2* uv_map = (const float2*)d_in[1];
    const float*  mask   = (const float*)d_in[2];
    float* out = (float*)d_out;

    int* counts = (int*)d_ws;                              // 256 ints
    unsigned int* entries = (unsigned int*)d_ws + 256;     // 256*CAP u32 = 4 MB

    hipMemsetAsync(counts, 0, NTILES * sizeof(int), stream);

    bin_kernel<<<NPIX / 256, 256, 0, stream>>>(uv_map, mask, counts, entries);
    gather_kernel<<<NTILES, 512, 0, stream>>>(f_map, uv_map, counts, entries, out);
}

// Round 7
// 125.468 us; speedup vs baseline: 3.6597x; 3.6597x over previous
//
#include <hip/hip_runtime.h>

#define TEX_H 256
#define TEX_W 256
#define FCH 16
#define NPIX (8 * 256 * 256)
#define TS 8                  // texel tile = 8x8
#define TROW 32               // 32x32 tiles
#define NTILES 1024
#define NREP 16               // replicated sub-buckets per tile (by blockIdx&15)
#define CAPR 64               // capacity per sub-bucket (mean ~25)
#define HS 10                 // halo grid = 10x10 centers (tile + 1 ring)

#define SQRT2_F 1.41421356237f
// Interior weights (du,dv exactly integer since grid anchored at u-2):
#define W_EDGE   0.24311673443f   // exp(-sqrt(2))
#define W_DIAG   0.13533528324f   // exp(-2)

// Entry: bit31 = boundary flag; bits30-27 = dr (center row - r0 + 1, 0..9);
// bits26-23 = dc; bits18-0 = pixel id (NPIX = 2^19).
__global__ __launch_bounds__(256) void bin_kernel(
    const float2* __restrict__ uv_map,
    const float*  __restrict__ mask,
    int*          __restrict__ counts,
    unsigned int* __restrict__ entries)
{
    int pix = blockIdx.x * 256 + threadIdx.x;   // grid exact: NPIX/256 blocks
    if (mask[pix] == 0.0f) return;

    float2 uv = uv_map[pix];
    float u = uv.x * 256.0f;
    float v = uv.y * 256.0f;
    bool bu = (u < 2.0f), bv = (v < 2.0f);
    int iu = (int)u, iv = (int)v;

    int clo, chi, rlo, rhi;
    if (!bu) { clo = iu - 1; chi = min(iu + 1, 255); } else { clo = 0; chi = 3; }
    if (!bv) { rlo = iv - 1; rhi = min(iv + 1, 255); } else { rlo = 0; rhi = 3; }

    unsigned bflag = (bu || bv) ? (1u << 31) : 0u;
    int rep = blockIdx.x & (NREP - 1);

    for (int tr = rlo >> 3; tr <= rhi >> 3; ++tr) {
        for (int tc = clo >> 3; tc <= chi >> 3; ++tc) {
            int ctr = (tr * TROW + tc) * NREP + rep;
            int slot = atomicAdd(&counts[ctr], 1);
            if (slot < CAPR) {
                unsigned ent;
                if (!bflag) {
                    unsigned dr = (unsigned)(iv - (tr << 3) + 1);   // 0..9
                    unsigned dc = (unsigned)(iu - (tc << 3) + 1);
                    ent = (dr << 27) | (dc << 23) | (unsigned)pix;
                } else {
                    ent = bflag | (unsigned)pix;
                }
                entries[ctr * CAPR + slot] = ent;
            }
        }
    }
}

// One WG (256 thr) per 8x8 tile. Interior entries: 1 LDS add into a 10x10
// per-center halo; then csum/wsum = 3x3 weighted conv of the halo (weights
// depend only on offset). Boundary entries: exact expf path into a direct
// accumulator. Merge, normalize, write 8 broadcast copies.
__global__ __launch_bounds__(256) void gather_kernel(
    const float*  __restrict__ f_map,
    const float2* __restrict__ uv_map,
    const int*    __restrict__ counts,
    const unsigned int* __restrict__ entries,
    float* __restrict__ out)
{
    __shared__ float s_halo[HS * HS * FCH];   // per-center feature sums (6.25 KB)
    __shared__ float s_hcnt[HS * HS];         // per-center counts
    __shared__ float s_dir[TS * TS * FCH];    // boundary-path direct csum (4 KB)
    __shared__ float s_dirw[TS * TS];

    for (int i = threadIdx.x; i < HS * HS * FCH; i += 256) s_halo[i] = 0.0f;
    for (int i = threadIdx.x; i < HS * HS;       i += 256) s_hcnt[i] = 0.0f;
    for (int i = threadIdx.x; i < TS * TS * FCH; i += 256) s_dir[i]  = 0.0f;
    for (int i = threadIdx.x; i < TS * TS;       i += 256) s_dirw[i] = 0.0f;
    __syncthreads();

    int tile = blockIdx.x;
    int r0 = (tile >> 5) << 3;
    int c0 = (tile & 31) << 3;
    int g = threadIdx.x >> 4;     // 16 entry-groups of 16 channel-lanes
    int c = threadIdx.x & 15;

    for (int rep = 0; rep < NREP; ++rep) {
        int ctr = tile * NREP + rep;
        int cnt = min(counts[ctr], CAPR);
        const unsigned int* eb = entries + ctr * CAPR;
        for (int e = g; e < cnt; e += 16) {
            unsigned ent = eb[e];
            unsigned pix = ent & 0x7FFFFu;
            float f = f_map[pix * FCH + c];     // 16 lanes -> one 64B line
            if (!(ent >> 31)) {
                int hr = (int)((ent >> 27) & 15u);      // halo row 0..9
                int hc = (int)((ent >> 23) & 15u);
                atomicAdd(&s_halo[(hr * HS + hc) * FCH + c], f);
                if (c == 0) atomicAdd(&s_hcnt[hr * HS + hc], 1.0f);
            } else {
                // Boundary pixel (u<2 or v<2): exact reference 4x4 window.
                float2 uvv = uv_map[pix];
                float u = uvv.x * 256.0f, v = uvv.y * 256.0f;
                float us = fmaxf(u - 2.0f, 0.0f);
                float vs = fmaxf(v - 2.0f, 0.0f);
                #pragma unroll
                for (int kv = 0; kv < 4; ++kv) {
                    float vg = vs + (float)kv;
                    int lr = (int)vg - r0;
                    if (lr < 0 || lr >= TS) continue;
                    float dvf = fabsf(vg - v);
                    #pragma unroll
                    for (int ku = 0; ku < 4; ++ku) {
                        float ug = us + (float)ku;
                        int lc = (int)ug - c0;
                        if (lc < 0 || lc >= TS) continue;
                        float duf = fabsf(ug - u);
                        float w = expf(-sqrtf(duf * duf + dvf * dvf) * SQRT2_F);
                        if (w > 0.1f) {
                            atomicAdd(&s_dir[(lr * TS + lc) * FCH + c], w * f);
                            if (c == 0) atomicAdd(&s_dirw[lr * TS + lc], w);
                        }
                    }
                }
            }
        }
    }
    __syncthreads();

    // 3x3 conv of halo + direct merge + normalize + 8-way broadcast write.
    // Thread t: channel c = t&15, texels tx = (t>>4) + 16k (4 texels each).
    for (int tx = threadIdx.x >> 4; tx < TS * TS; tx += 16) {
        int row = tx >> 3, col = tx & 7;
        float cs = s_dir[tx * FCH + c];
        float ws = s_dirw[tx];
        #pragma unroll
        for (int dv = 0; dv < 3; ++dv) {
            #pragma unroll
            for (int du = 0; du < 3; ++du) {
                float w = (dv == 1 && du == 1) ? 1.0f
                        : ((dv == 1 || du == 1) ? W_EDGE : W_DIAG);
                int h = (row + dv) * HS + (col + du);
                cs += w * s_halo[h * FCH + c];
                ws += w * s_hcnt[h];
            }
        }
        float s = (ws > 0.01f) ? (1.0f / (ws + 0.001f)) : 0.0f;
        float val = cs * s;
        size_t base = ((size_t)(r0 + row) * 256 + (c0 + col)) * FCH + c;
        #pragma unroll
        for (int b = 0; b < 8; ++b) {
            out[(size_t)b * (256 * 256 * FCH) + base] = val;
        }
    }
}

extern "C" void kernel_launch(void* const* d_in, const int* in_sizes, int n_in,
                              void* d_out, int out_size, void* d_ws, size_t ws_size,
                              hipStream_t stream) {
    const float*  f_map  = (const float*)d_in[0];
    const float2* uv_map = (const float2*)d_in[1];
    const float*  mask   = (const float*)d_in[2];
    float* out = (float*)d_out;

    int* counts = (int*)d_ws;                                   // 16384 ints (64 KB)
    unsigned int* entries = (unsigned int*)d_ws + NTILES * NREP; // 16384*64 u32 = 4 MB

    hipMemsetAsync(counts, 0, NTILES * NREP * sizeof(int), stream);

    bin_kernel<<<NPIX / 256, 256, 0, stream>>>(uv_map, mask, counts, entries);
    gather_kernel<<<NTILES, 256, 0, stream>>>(f_map, uv_map, counts, entries, out);
}

// Round 9
// 117.770 us; speedup vs baseline: 3.8989x; 1.0654x over previous
//
#include <hip/hip_runtime.h>

#define TEX_H 256
#define TEX_W 256
#define FCH 16
#define NPIX (8 * 256 * 256)
#define TS 8                  // texel tile = 8x8
#define TROW 32               // 32x32 tiles
#define NTILES 1024
#define NREP 16               // replicated sub-buckets per tile
#define CAPR 64               // capacity per sub-bucket (mean ~22, max ~31 on edge tiles)
#define HS 10                 // halo grid = 10x10 centers (tile + 1 ring)

#define SQRT2_F 1.41421356237f
// Interior weights (du,dv exactly integer since grid anchored at u-2):
#define W_EDGE   0.24311673443f   // exp(-sqrt(2))
#define W_DIAG   0.13533528324f   // exp(-2)

// Entry: bit31 = boundary flag; bits30-27 = dr (center row - r0 + 1, 0..9);
// bits26-23 = dc; bits18-0 = pixel id (NPIX = 2^19).
__global__ __launch_bounds__(256) void bin_kernel(
    const float2* __restrict__ uv_map,
    const float*  __restrict__ mask,
    int*          __restrict__ counts,
    unsigned int* __restrict__ entries)
{
    int pix = blockIdx.x * 256 + threadIdx.x;   // grid exact: NPIX/256 blocks
    if (mask[pix] == 0.0f) return;

    float2 uv = uv_map[pix];
    float u = uv.x * 256.0f;
    float v = uv.y * 256.0f;
    bool bu = (u < 2.0f), bv = (v < 2.0f);
    int iu = (int)u, iv = (int)v;

    int clo, chi, rlo, rhi;
    if (!bu) { clo = iu - 1; chi = min(iu + 1, 255); } else { clo = 0; chi = 3; }
    if (!bv) { rlo = iv - 1; rhi = min(iv + 1, 255); } else { rlo = 0; rhi = 3; }

    unsigned bflag = (bu || bv) ? (1u << 31) : 0u;
    int rep = pix & (NREP - 1);                 // fine-grained spread across reps

    for (int tr = rlo >> 3; tr <= rhi >> 3; ++tr) {
        for (int tc = clo >> 3; tc <= chi >> 3; ++tc) {
            int ctr = (tr * TROW + tc) * NREP + rep;
            int slot = atomicAdd(&counts[ctr], 1);
            if (slot < CAPR) {
                unsigned ent;
                if (!bflag) {
                    unsigned dr = (unsigned)(iv - (tr << 3) + 1);   // 0..9
                    unsigned dc = (unsigned)(iu - (tc << 3) + 1);
                    ent = (dr << 27) | (dc << 23) | (unsigned)pix;
                } else {
                    ent = bflag | (unsigned)pix;
                }
                entries[ctr * CAPR + slot] = ent;
            }
        }
    }
}

// One WG (512 thr = 32 groups of 16 channel-lanes) per 8x8 tile.
// Group g owns rep g>>1, parity g&1 -> all rep lists drain concurrently.
// Interior entries: 1 LDS add into 10x10 per-center halo; csum/wsum then =
// 3x3 weighted conv of the halo. Boundary entries: exact expf path.
__global__ __launch_bounds__(512) void gather_kernel(
    const float*  __restrict__ f_map,
    const float2* __restrict__ uv_map,
    const int*    __restrict__ counts,
    const unsigned int* __restrict__ entries,
    float* __restrict__ out)
{
    __shared__ float s_halo[HS * HS * FCH];   // per-center feature sums (6.25 KB)
    __shared__ float s_hcnt[HS * HS];
    __shared__ float s_dir[TS * TS * FCH];    // boundary-path direct csum (4 KB)
    __shared__ float s_dirw[TS * TS];

    for (int i = threadIdx.x; i < HS * HS * FCH; i += 512) s_halo[i] = 0.0f;
    for (int i = threadIdx.x; i < HS * HS;       i += 512) s_hcnt[i] = 0.0f;
    for (int i = threadIdx.x; i < TS * TS * FCH; i += 512) s_dir[i]  = 0.0f;
    for (int i = threadIdx.x; i < TS * TS;       i += 512) s_dirw[i] = 0.0f;
    __syncthreads();

    int tile = blockIdx.x;
    int r0 = (tile >> 5) << 3;
    int c0 = (tile & 31) << 3;
    int c     = threadIdx.x & 15;
    int group = threadIdx.x >> 4;    // 0..31
    int rep   = group >> 1;
    int par   = group & 1;

    int ctr = tile * NREP + rep;
    int cnt = min(counts[ctr], CAPR);
    const unsigned int* mb = entries + ctr * CAPR;

    auto process = [&](unsigned ent, float f) {
        if (!(ent >> 31)) {
            int hr = (int)((ent >> 27) & 15u);
            int hc = (int)((ent >> 23) & 15u);
            atomicAdd(&s_halo[(hr * HS + hc) * FCH + c], f);
            if (c == 0) atomicAdd(&s_hcnt[hr * HS + hc], 1.0f);
        } else {
            unsigned pix = ent & 0x7FFFFu;
            float2 uvv = uv_map[pix];
            float u = uvv.x * 256.0f, v = uvv.y * 256.0f;
            float us = fmaxf(u - 2.0f, 0.0f);
            float vs = fmaxf(v - 2.0f, 0.0f);
            #pragma unroll
            for (int kv = 0; kv < 4; ++kv) {
                float vg = vs + (float)kv;
                int lr = (int)vg - r0;
                if (lr < 0 || lr >= TS) continue;
                float dvf = fabsf(vg - v);
                #pragma unroll
                for (int ku = 0; ku < 4; ++ku) {
                    float ug = us + (float)ku;
                    int lc = (int)ug - c0;
                    if (lc < 0 || lc >= TS) continue;
                    float duf = fabsf(ug - u);
                    float w = expf(-sqrtf(duf * duf + dvf * dvf) * SQRT2_F);
                    if (w > 0.1f) {
                        atomicAdd(&s_dir[(lr * TS + lc) * FCH + c], w * f);
                        if (c == 0) atomicAdd(&s_dirw[lr * TS + lc], w);
                    }
                }
            }
        }
    };

    // 2-way unrolled drain of this group's (rep, parity) slice: two independent
    // meta loads then two independent 64B f_map gathers in flight.
    int e = par;
    for (; e + 2 < cnt; e += 4) {
        unsigned ent0 = mb[e];
        unsigned ent1 = mb[e + 2];
        float f0 = f_map[(ent0 & 0x7FFFFu) * FCH + c];
        float f1 = f_map[(ent1 & 0x7FFFFu) * FCH + c];
        process(ent0, f0);
        process(ent1, f1);
    }
    for (; e < cnt; e += 2) {
        unsigned ent0 = mb[e];
        float f0 = f_map[(ent0 & 0x7FFFFu) * FCH + c];
        process(ent0, f0);
    }
    __syncthreads();

    // 3x3 conv of halo + direct merge + normalize + 8-way broadcast write.
    for (int tx = group; tx < TS * TS; tx += 32) {
        int row = tx >> 3, col = tx & 7;
        float cs = s_dir[tx * FCH + c];
        float ws = s_dirw[tx];
        #pragma unroll
        for (int dv = 0; dv < 3; ++dv) {
            #pragma unroll
            for (int du = 0; du < 3; ++du) {
                float w = (dv == 1 && du == 1) ? 1.0f
                        : ((dv == 1 || du == 1) ? W_EDGE : W_DIAG);
                int h = (row + dv) * HS + (col + du);
                cs += w * s_halo[h * FCH + c];
                ws += w * s_hcnt[h];
            }
        }
        float s = (ws > 0.01f) ? (1.0f / (ws + 0.001f)) : 0.0f;
        float val = cs * s;
        size_t base = ((size_t)(r0 + row) * 256 + (c0 + col)) * FCH + c;
        #pragma unroll
        for (int b = 0; b < 8; ++b) {
            out[(size_t)b * (256 * 256 * FCH) + base] = val;
        }
    }
}

extern "C" void kernel_launch(void* const* d_in, const int* in_sizes, int n_in,
                              void* d_out, int out_size, void* d_ws, size_t ws_size,
                              hipStream_t stream) {
    const float*  f_map  = (const float*)d_in[0];
    const float2* uv_map = (const float2*)d_in[1];
    const float*  mask   = (const float*)d_in[2];
    float* out = (float*)d_out;

    int* counts = (int*)d_ws;                                    // 16384 ints (64 KB)
    unsigned int* entries = (unsigned int*)d_ws + NTILES * NREP; // 16384*64 u32 = 4 MB

    hipMemsetAsync(counts, 0, NTILES * NREP * sizeof(int), stream);

    bin_kernel<<<NPIX / 256, 256, 0, stream>>>(uv_map, mask, counts, entries);
    gather_kernel<<<NTILES, 512, 0, stream>>>(f_map, uv_map, counts, entries, out);
}

// Round 10
// 61.290 us; speedup vs baseline: 7.4919x; 1.9215x over previous
//
#include <hip/hip_runtime.h>

#define TEX_H 256
#define TEX_W 256
#define FCH 16
#define NPIX (8 * 256 * 256)

#define SQRT2_F 1.41421356237f
// Interior weights (grid anchored at u-2 => du,dv exactly in {0,1,2};
// d=2 slots fail w>0.1, leaving the 3x3 with constant weights):
#define W_EDGE   0.24311673443f   // exp(-sqrt(2))
#define W_DIAG   0.13533528324f   // exp(-2)

// Workspace layout (total 4,595,712 B):
//  halo_c [256*256*16] f32  per-center channel sums        @ 0
//  halo_n [256*256]    f32  per-center counts              @ 4,194,304
//  dir_c  [2*4*256*16] f32  boundary strips (ui<4 | vi<4)  @ 4,456,448
//  dir_w  [2*4*256]    f32                                 @ 4,587,520
#define HALO_C_OFF 0
#define HALO_N_OFF (256 * 256 * 16)
#define DIR_C_OFF  (HALO_N_OFF + 256 * 256)
#define DIR_W_OFF  (DIR_C_OFF + 2 * 4 * 256 * 16)
#define WS_FLOATS  (DIR_W_OFF + 2 * 4 * 256)

// 16 threads per pixel (one per channel). Interior pixel: ONE atomic per
// channel into its center cell (+1 count on lane 0) -- the 3x3 weighting is
// deferred to a convolution in finalize. Boundary pixel (u<2 or v<2): exact
// reference 4x4 expf window into compact edge strips.
__global__ __launch_bounds__(256) void splat_kernel(
    const float*  __restrict__ f_map,
    const float2* __restrict__ uv_map,
    const float*  __restrict__ mask,
    float* __restrict__ ws)
{
    int tid = blockIdx.x * 256 + threadIdx.x;
    int pix = tid >> 4;
    int c   = tid & 15;

    if (mask[pix] == 0.0f) return;

    float2 uv = uv_map[pix];
    float u = uv.x * 256.0f;
    float v = uv.y * 256.0f;
    float f = f_map[pix * FCH + c];

    if (u >= 2.0f && v >= 2.0f) {
        int iu = (int)u, iv = (int)v;   // center cell; iu,iv <= 255 (uv < 1)
        unsafeAtomicAdd(&ws[HALO_C_OFF + (iv * 256 + iu) * FCH + c], f);
        if (c == 0) unsafeAtomicAdd(&ws[HALO_N_OFF + iv * 256 + iu], 1.0f);
    } else {
        // Exact reference path. All passing slots have ui<4 (when u<2) or
        // vi<4 (when v<2, ui>=4) -> compact strip accumulators.
        float us = fmaxf(u - 2.0f, 0.0f);
        float vs = fmaxf(v - 2.0f, 0.0f);
        #pragma unroll
        for (int kv = 0; kv < 4; ++kv) {
            float vg = vs + (float)kv;
            int vi = (int)vg;
            float dvf = fabsf(vg - v);
            #pragma unroll
            for (int ku = 0; ku < 4; ++ku) {
                float ug = us + (float)ku;
                int ui = (int)ug;
                float duf = fabsf(ug - u);
                float w = expf(-sqrtf(duf * duf + dvf * dvf) * SQRT2_F);
                if (w > 0.1f && vi < TEX_H && ui < TEX_W) {
                    int cell = (ui < 4) ? (ui * 256 + vi)            // region 0
                                        : ((4 + vi) * 256 + ui);     // region 1 (vi<4)
                    unsafeAtomicAdd(&ws[DIR_C_OFF + cell * FCH + c], w * f);
                    if (c == 0) unsafeAtomicAdd(&ws[DIR_W_OFF + cell], w);
                }
            }
        }
    }
}

// 1024 WGs x 256 threads; WG = 8x8 texel tile; thread = (texel 0..63, c4 0..3).
// csum(texel) = sum over 3x3 neighbor centers of w(|a|,|b|) * halo_c[center]
// (+ boundary strip), wsum analogous with halo_n. Normalize, write 8 copies.
__global__ __launch_bounds__(256) void finalize_kernel(
    const float* __restrict__ ws,
    float* __restrict__ out)
{
    int tile = blockIdx.x;                  // 32x32 tiles of 8x8
    int r0 = (tile >> 5) << 3;
    int c0 = (tile & 31) << 3;
    int tx = threadIdx.x >> 2;              // texel in tile 0..63
    int c4 = threadIdx.x & 3;               // float4 chunk 0..3
    int gr = r0 + (tx >> 3);
    int gc = c0 + (tx & 7);

    float4 cs = make_float4(0.f, 0.f, 0.f, 0.f);
    float wsm = 0.0f;

    #pragma unroll
    for (int a = -1; a <= 1; ++a) {
        int cr = gr + a;
        if (cr < 0 || cr > 255) continue;
        #pragma unroll
        for (int b = -1; b <= 1; ++b) {
            int cc = gc + b;
            if (cc < 0 || cc > 255) continue;
            float w = (a == 0 && b == 0) ? 1.0f
                    : ((a == 0 || b == 0) ? W_EDGE : W_DIAG);
            int cell = cr * 256 + cc;
            float4 h = *(const float4*)&ws[HALO_C_OFF + cell * FCH + c4 * 4];
            cs.x += w * h.x; cs.y += w * h.y; cs.z += w * h.z; cs.w += w * h.w;
            wsm  += w * ws[HALO_N_OFF + cell];
        }
    }

    // Boundary strip merge (matches splat's region assignment exactly).
    if (gc < 4) {
        int cell = gc * 256 + gr;
        float4 d = *(const float4*)&ws[DIR_C_OFF + cell * FCH + c4 * 4];
        cs.x += d.x; cs.y += d.y; cs.z += d.z; cs.w += d.w;
        wsm  += ws[DIR_W_OFF + cell];
    } else if (gr < 4) {
        int cell = (4 + gr) * 256 + gc;
        float4 d = *(const float4*)&ws[DIR_C_OFF + cell * FCH + c4 * 4];
        cs.x += d.x; cs.y += d.y; cs.z += d.z; cs.w += d.w;
        wsm  += ws[DIR_W_OFF + cell];
    }

    float s = (wsm > 0.01f) ? (1.0f / (wsm + 0.001f)) : 0.0f;
    cs.x *= s; cs.y *= s; cs.z *= s; cs.w *= s;

    size_t base = ((size_t)gr * 256 + gc) * FCH + c4 * 4;
    #pragma unroll
    for (int b = 0; b < 8; ++b) {
        *(float4*)&out[(size_t)b * (256 * 256 * FCH) + base] = cs;
    }
}

extern "C" void kernel_launch(void* const* d_in, const int* in_sizes, int n_in,
                              void* d_out, int out_size, void* d_ws, size_t ws_size,
                              hipStream_t stream) {
    const float*  f_map  = (const float*)d_in[0];
    const float2* uv_map = (const float2*)d_in[1];
    const float*  mask   = (const float*)d_in[2];
    float* out = (float*)d_out;
    float* ws  = (float*)d_ws;

    hipMemsetAsync(ws, 0, (size_t)WS_FLOATS * sizeof(float), stream);

    splat_kernel<<<(NPIX * 16) / 256, 256, 0, stream>>>(f_map, uv_map, mask, ws);
    finalize_kernel<<<1024, 256, 0, stream>>>(ws, out);
}